// Round 4
// baseline (208.491 us; speedup 1.0000x reference)
//
#include <hip/hip_runtime.h>
#include <hip/hip_bf16.h>
#include <stdint.h>

using bf16x8 = __attribute__((ext_vector_type(8))) __bf16;
using f32x4  = __attribute__((ext_vector_type(4))) float;
using i32x4  = __attribute__((ext_vector_type(4))) int;

#define BM 128
#define BN 64
#define BK 64
#define NTHR 512   // 8 waves: 4 (M) x 2 (N); wave tile 32x32

__device__ __forceinline__ void gload_lds16(const void* g, void* l) {
  __builtin_amdgcn_global_load_lds((const __attribute__((address_space(1))) void*)g,
                                   (__attribute__((address_space(3))) void*)l,
                                   16, 0, 0);
}

// out[M,N] = x[M,K] @ W^T + bias,  W[n,k] = qw[n,k] * scales[n, k/GS]
// A staged as bf16 (from prepass buffer xb if XBF, else reg-staged from x).
// B staged RAW int32 via global_load_lds; dequant at fragment build.
template<bool XBF>
__global__ __launch_bounds__(NTHR, 4)
void gptq_gemm(const float* __restrict__ x, const __bf16* __restrict__ xb,
               const int* __restrict__ qw, const float* __restrict__ scales,
               const float* __restrict__ bias, float* __restrict__ out,
               int M, int N, int K, int NG, int GS, int gy) {
  __shared__ __bf16 As[2][BM * BK];   // 32 KiB (swizzled 16B units)
  __shared__ int    Bs[2][BN * BK];   // 32 KiB (raw int32, swizzled 16B units)

  const int tid  = threadIdx.x;
  const int lane = tid & 63;
  const int wave = tid >> 6;
  const int wr   = wave >> 1;     // 0..3
  const int wc   = wave & 1;      // 0..1

  // by-fast: consecutive blocks share one qweight panel (L3 temporal reuse)
  const int bx = blockIdx.x / gy;
  const int by = blockIdx.x % gy;
  const int tileM = by * BM;
  const int tileN = bx * BN;

  const int l15 = lane & 15;
  const int l4  = lane >> 4;      // 0..3

  f32x4 acc[2][2];
#pragma unroll
  for (int m = 0; m < 2; ++m)
#pragma unroll
    for (int n = 0; n < 2; ++n)
      acc[m][n] = (f32x4)0.0f;

  // ---- staging: 16B units, source pre-swizzled so LDS stays linear ----
  // A: unit u -> row=u>>3, slot=u&7 holds global k-group c8 = slot^(row&7)
  // B: unit u -> row=u>>4, slot4=u&15 holds global int4-group c4 = slot4^(row&7)
  auto STAGE = [&](int buf, int k0) {
#pragma unroll
    for (int i = 0; i < 2; ++i) {
      const int u = (i * 8 + wave) * 64 + lane;
      if (XBF) {
        const int row = u >> 3, slot = u & 7;
        const int c8 = slot ^ (row & 7);
        gload_lds16(xb + (size_t)(tileM + row) * K + k0 + c8 * 8,
                    &As[buf][(i * 8 + wave) * 512]);
      }
      {
        const int row = u >> 4, slot4 = u & 15;
        const int c4 = slot4 ^ (row & 7);
        gload_lds16(qw + (size_t)(tileN + row) * K + k0 + c4 * 4,
                    &Bs[buf][(i * 8 + wave) * 256]);
      }
    }
  };

  // fallback A path: reg-stage fp32 -> bf16 (2 loads/thread)
  const int srow = tid >> 3;      // 0..63
  const int sc8  = tid & 7;
  auto loadA = [&](int k0, f32x4 (&va)[2][2]) {
#pragma unroll
    for (int i = 0; i < 2; ++i) {
      const f32x4* p = reinterpret_cast<const f32x4*>(
          x + (size_t)(tileM + i * 64 + srow) * K + k0 + sc8 * 8);
      va[i][0] = p[0]; va[i][1] = p[1];
    }
  };
  auto writeA = [&](int buf, const f32x4 (&va)[2][2]) {
#pragma unroll
    for (int i = 0; i < 2; ++i) {
      const int row = i * 64 + srow;
      const int slot = sc8 ^ (row & 7);
      bf16x8 w;
      w[0] = (__bf16)va[i][0][0]; w[1] = (__bf16)va[i][0][1];
      w[2] = (__bf16)va[i][0][2]; w[3] = (__bf16)va[i][0][3];
      w[4] = (__bf16)va[i][1][0]; w[5] = (__bf16)va[i][1][1];
      w[6] = (__bf16)va[i][1][2]; w[7] = (__bf16)va[i][1][3];
      *reinterpret_cast<bf16x8*>(&As[buf][row * BK + slot * 8]) = w;
    }
  };

  // scales: per-lane row pointers; prefetch next group's scale into regs
  const float* sp0 = scales + (size_t)(tileN + wc * 32 + l15) * NG;
  const float* sp1 = scales + (size_t)(tileN + wc * 32 + 16 + l15) * NG;
  const int gpg = GS / BK;        // K-steps per scale group (=2)
  const int nT  = K / BK;

  // ---- prologue: stage tile 0 ----
  if (XBF) {
    STAGE(0, 0);
  } else {
    f32x4 v0[2][2];
    loadA(0, v0);
    STAGE(0, 0);          // B only (A guarded by XBF inside)
    writeA(0, v0);
  }
  float s_c0 = sp0[0], s_c1 = sp1[0], s_n0 = 0.f, s_n1 = 0.f;
  __syncthreads();        // drains vmcnt(0): tile 0 landed

  int cur = 0;
  for (int t = 0; t < nT; ++t) {
    const bool pf = (t + 1) < nT;
    f32x4 va[2][2];
    if (!XBF && pf) loadA((t + 1) * BK, va);
    if (pf) STAGE(cur ^ 1, (t + 1) * BK);   // fire-and-forget, no VGPR cost
    if (t % gpg == 0) {
      int gn = t / gpg + 1; if (gn > NG - 1) gn = NG - 1;
      s_n0 = sp0[gn]; s_n1 = sp1[gn];
    }

    // ---- MFMA phase on buf[cur]: frag build + dequant + mfma ----
#pragma unroll
    for (int kk = 0; kk < 2; ++kk) {
      const int c8 = kk * 4 + l4;
      bf16x8 af[2];
#pragma unroll
      for (int m = 0; m < 2; ++m) {
        const int r = wr * 32 + m * 16 + l15;
        const int slot = c8 ^ (r & 7);
        af[m] = *reinterpret_cast<const bf16x8*>(&As[cur][r * BK + slot * 8]);
      }
#pragma unroll
      for (int n = 0; n < 2; ++n) {
        const int r = wc * 32 + n * 16 + l15;
        const int rb = r & 7;
        const int u0 = (2 * c8) ^ rb, u1 = (2 * c8 + 1) ^ rb;
        i32x4 q0 = *reinterpret_cast<const i32x4*>(&Bs[cur][r * BK + u0 * 4]);
        i32x4 q1 = *reinterpret_cast<const i32x4*>(&Bs[cur][r * BK + u1 * 4]);
        const float s = n ? s_c1 : s_c0;
        bf16x8 bb;
        bb[0] = (__bf16)((float)q0[0] * s); bb[1] = (__bf16)((float)q0[1] * s);
        bb[2] = (__bf16)((float)q0[2] * s); bb[3] = (__bf16)((float)q0[3] * s);
        bb[4] = (__bf16)((float)q1[0] * s); bb[5] = (__bf16)((float)q1[1] * s);
        bb[6] = (__bf16)((float)q1[2] * s); bb[7] = (__bf16)((float)q1[3] * s);
        acc[0][n] = __builtin_amdgcn_mfma_f32_16x16x32_bf16(af[0], bb, acc[0][n], 0, 0, 0);
        acc[1][n] = __builtin_amdgcn_mfma_f32_16x16x32_bf16(af[1], bb, acc[1][n], 0, 0, 0);
      }
    }

    if (!XBF && pf) writeA(cur ^ 1, va);
    if (t % gpg == gpg - 1) { s_c0 = s_n0; s_c1 = s_n1; }
    __syncthreads();        // compiler emits vmcnt(0): tile t+1 landed
    cur ^= 1;
  }

  // ---- epilogue: D row = l4*4 + r, col = l15 ----
#pragma unroll
  for (int n = 0; n < 2; ++n) {
    const int col = tileN + wc * 32 + n * 16 + l15;
    const float bv = bias[col];
#pragma unroll
    for (int m = 0; m < 2; ++m) {
      const int rbase = tileM + wr * 32 + m * 16 + l4 * 4;
#pragma unroll
      for (int r = 0; r < 4; ++r)
        out[(size_t)(rbase + r) * N + col] = acc[m][n][r] + bv;
    }
  }
}

// prepass: x fp32 -> bf16 into workspace
__global__ __launch_bounds__(256)
void xcvt(const float* __restrict__ x, __bf16* __restrict__ xb, int n8) {
  const int i = blockIdx.x * blockDim.x + threadIdx.x;
  if (i < n8) {
    const f32x4* p = reinterpret_cast<const f32x4*>(x + (size_t)i * 8);
    f32x4 a = p[0], b = p[1];
    bf16x8 w;
    w[0] = (__bf16)a[0]; w[1] = (__bf16)a[1]; w[2] = (__bf16)a[2]; w[3] = (__bf16)a[3];
    w[4] = (__bf16)b[0]; w[5] = (__bf16)b[1]; w[6] = (__bf16)b[2]; w[7] = (__bf16)b[3];
    *reinterpret_cast<bf16x8*>(xb + (size_t)i * 8) = w;
  }
}

extern "C" void kernel_launch(void* const* d_in, const int* in_sizes, int n_in,
                              void* d_out, int out_size, void* d_ws, size_t ws_size,
                              hipStream_t stream) {
  const float* x      = (const float*)d_in[0];
  const int*   qw     = (const int*)d_in[1];
  const float* scales = (const float*)d_in[2];
  const float* bias   = (const float*)d_in[3];
  float*       out    = (float*)d_out;

  const int OUT = in_sizes[3];            // 11008
  const int IN  = in_sizes[1] / OUT;      // 4096
  const int M   = in_sizes[0] / IN;       // 512
  const int NG  = in_sizes[2] / OUT;      // 32
  const int GS  = IN / NG;                // 128

  const int gx = OUT / BN;                // 172
  const int gy = M / BM;                  // 4

  const size_t need = (size_t)M * IN * sizeof(__bf16);
  const bool xbf = (ws_size >= need) && ((M * IN) % 2048 == 0);

  if (xbf) {
    const int n8 = (M * IN) / 8;
    xcvt<<<(n8 + 255) / 256, 256, 0, stream>>>(x, (__bf16*)d_ws, n8);
    gptq_gemm<true><<<gx * gy, NTHR, 0, stream>>>(
        x, (const __bf16*)d_ws, qw, scales, bias, out, M, OUT, IN, NG, GS, gy);
  } else {
    gptq_gemm<false><<<gx * gy, NTHR, 0, stream>>>(
        x, nullptr, qw, scales, bias, out, M, OUT, IN, NG, GS, gy);
  }
}

// Round 5
// 172.958 us; speedup vs baseline: 1.2054x; 1.2054x over previous
//
#include <hip/hip_runtime.h>
#include <hip/hip_bf16.h>
#include <stdint.h>

using bf16x8 = __attribute__((ext_vector_type(8))) __bf16;
using f32x4  = __attribute__((ext_vector_type(4))) float;
using i32x4  = __attribute__((ext_vector_type(4))) int;
using f32x2  = __attribute__((ext_vector_type(2))) float;

#define BM 128
#define BN 64
#define BK 64
#define NTHR 512   // 8 waves: 2 (M) x 4 (N); wave tile 64x16

__device__ __forceinline__ void gload_lds16(const void* g, void* l) {
  __builtin_amdgcn_global_load_lds((const __attribute__((address_space(1))) void*)g,
                                   (__attribute__((address_space(3))) void*)l,
                                   16, 0, 0);
}

// ---------------- pipelined kernel (A pre-converted to bf16 in ws) ----------
__global__ __launch_bounds__(NTHR, 4)
void gptq_gemm_pipe(const __bf16* __restrict__ xb, const int* __restrict__ qw,
                    const float* __restrict__ scales, const float* __restrict__ bias,
                    float* __restrict__ out, int M, int N, int K, int NG, int gy) {
  __shared__ __bf16 As[2][BM * BK];   // 2 x 16 KiB
  __shared__ int    Bs[2][BN * BK];   // 2 x 16 KiB (raw int32)

  const int tid  = threadIdx.x;
  const int lane = tid & 63;
  const int wave = tid >> 6;
  const int wr   = wave >> 2;   // 0..1 (M)
  const int wc   = wave & 3;    // 0..3 (N)

  const int bx = blockIdx.x / gy;     // by-fast: panel sharers adjacent
  const int by = blockIdx.x % gy;
  const int tileM = by * BM;
  const int tileN = bx * BN;

  const int l15 = lane & 15;
  const int l4  = lane >> 4;

  f32x4 accf[4], part[4];
#pragma unroll
  for (int m = 0; m < 4; ++m) { accf[m] = (f32x4)0.0f; part[m] = (f32x4)0.0f; }

  // staging: 16B units; LDS linear, global source pre-swizzled (m173 pattern)
  auto STAGE = [&](int buf, int t) {
    const int k0 = t * BK;
#pragma unroll
    for (int i = 0; i < 2; ++i) {
      const int u = (i * 8 + wave) * 64 + lane;
      { // A: row=u>>3, slot=u&7 holds global c8 = slot^(row&7)
        const int row = u >> 3, slot = u & 7;
        const int c8 = slot ^ (row & 7);
        gload_lds16(xb + (size_t)(tileM + row) * K + k0 + c8 * 8,
                    &As[buf][(i * 8 + wave) * 512]);
      }
      { // B: row=u>>4, slot4=u&15 holds global c4 = slot4^(row&7)
        const int row = u >> 4, slot4 = u & 15;
        const int c4 = slot4 ^ (row & 7);
        gload_lds16(qw + (size_t)(tileN + row) * K + k0 + c4 * 4,
                    &Bs[buf][(i * 8 + wave) * 256]);
      }
    }
  };

  // per K-step compute: frag build (unscaled dequant) + MFMA into part[]
  auto MFMA_PHASE = [&](const __bf16* As_, const int* Bs_) {
#pragma unroll
    for (int kk = 0; kk < 2; ++kk) {
      const int c8 = kk * 4 + l4;
      bf16x8 af[4];
#pragma unroll
      for (int m = 0; m < 4; ++m) {
        const int row = wr * 64 + m * 16 + l15;
        const int slot = c8 ^ (row & 7);
        af[m] = *reinterpret_cast<const bf16x8*>(&As_[row * BK + slot * 8]);
      }
      const int r  = wc * 16 + l15;
      const int rb = r & 7;
      i32x4 q0 = *reinterpret_cast<const i32x4*>(&Bs_[r * BK + ((2 * c8) ^ rb) * 4]);
      i32x4 q1 = *reinterpret_cast<const i32x4*>(&Bs_[r * BK + ((2 * c8 + 1) ^ rb) * 4]);
      bf16x8 bb;   // q in [0,16): exact in bf16; scale applied per group later
      bb[0] = (__bf16)(float)q0[0]; bb[1] = (__bf16)(float)q0[1];
      bb[2] = (__bf16)(float)q0[2]; bb[3] = (__bf16)(float)q0[3];
      bb[4] = (__bf16)(float)q1[0]; bb[5] = (__bf16)(float)q1[1];
      bb[6] = (__bf16)(float)q1[2]; bb[7] = (__bf16)(float)q1[3];
#pragma unroll
      for (int m = 0; m < 4; ++m)
        part[m] = __builtin_amdgcn_mfma_f32_16x16x32_bf16(af[m], bb, part[m], 0, 0, 0);
    }
  };

  // per-lane scale pointer: col = tileN + wc*16 + l15
  const float* sPtr = scales + (size_t)(tileN + wc * 16 + l15) * NG;

  // ---- prologue: issue order pinned -> FIFO [L0(4), S01(1), L1(4), S2(1)] ----
  STAGE(0, 0);
  __builtin_amdgcn_sched_barrier(0);
  f32x2 s01 = *reinterpret_cast<const f32x2*>(sPtr);       // g0, g1
  __builtin_amdgcn_sched_barrier(0);
  STAGE(1, 1);
  __builtin_amdgcn_sched_barrier(0);
  float s_n2 = sPtr[NG > 2 ? 2 : NG - 1];                  // g2
  __builtin_amdgcn_sched_barrier(0);
  float s_cur = s01[0], s_nxt = s01[1], s_nxt2 = s_n2;

  const int nT = K / BK;   // even (K % 128 == 0)
  for (int t = 0; t < nT; t += 2) {
    // ---------- even step: buf 0 ----------
    asm volatile("s_waitcnt vmcnt(5)" ::: "memory");       // tile t landed
    __builtin_amdgcn_s_barrier();
    __builtin_amdgcn_sched_barrier(0);
    MFMA_PHASE(As[0], Bs[0]);
    __builtin_amdgcn_sched_barrier(0);
    __builtin_amdgcn_s_barrier();                          // buf 0 free
    if (t + 2 < nT) STAGE(0, t + 2);
    __builtin_amdgcn_sched_barrier(0);

    // ---------- odd step: buf 1 ----------
    if (t + 2 < nT) { asm volatile("s_waitcnt vmcnt(5)" ::: "memory"); }
    else            { asm volatile("s_waitcnt vmcnt(0)" ::: "memory"); }
    __builtin_amdgcn_s_barrier();
    __builtin_amdgcn_sched_barrier(0);
    MFMA_PHASE(As[1], Bs[1]);
    __builtin_amdgcn_sched_barrier(0);
    __builtin_amdgcn_s_barrier();                          // buf 1 free
    if (t + 3 < nT) STAGE(1, t + 3);
    __builtin_amdgcn_sched_barrier(0);

    // ---------- group boundary (GS = 2*BK): scale partials into accf ----------
#pragma unroll
    for (int m = 0; m < 4; ++m) {
      accf[m] += s_cur * part[m];
      part[m] = (f32x4)0.0f;
    }
    s_cur = s_nxt; s_nxt = s_nxt2;
    int g3 = (t >> 1) + 3; if (g3 > NG - 1) g3 = NG - 1;
    s_nxt2 = sPtr[g3];                                     // 1 VMEM after STAGE (count model)
  }

  // ---- epilogue: D row = l4*4 + r, col = l15 ----
  const int col = tileN + wc * 16 + l15;
  const float bv = bias[col];
#pragma unroll
  for (int m = 0; m < 4; ++m) {
    const int rbase = tileM + wr * 64 + m * 16 + l4 * 4;
#pragma unroll
    for (int r = 0; r < 4; ++r)
      out[(size_t)(rbase + r) * N + col] = accf[m][r] + bv;
  }
}

// ---------------- fallback (no usable ws): R1-style, known-correct ----------
#define FBM 128
#define FBN 128
__global__ __launch_bounds__(256)
void gptq_gemm_fb(const float* __restrict__ x, const int* __restrict__ qw,
                  const float* __restrict__ scales, const float* __restrict__ bias,
                  float* __restrict__ out, int M, int N, int K, int NG, int GS) {
  __shared__ __bf16 lds_a[FBM * BK];
  __shared__ __bf16 lds_b[FBN * BK];
  const int tid = threadIdx.x, lane = tid & 63, wave = tid >> 6;
  const int wr = wave >> 1, wc = wave & 1;
  const int tileM = blockIdx.y * FBM, tileN = blockIdx.x * FBN;
  const int l15 = lane & 15, l4 = lane >> 4;
  f32x4 acc[4][4];
#pragma unroll
  for (int m = 0; m < 4; ++m)
#pragma unroll
    for (int n = 0; n < 4; ++n) acc[m][n] = (f32x4)0.0f;
  for (int k0 = 0; k0 < K; k0 += BK) {
    const int g = k0 / GS;
#pragma unroll
    for (int i = 0; i < 4; ++i) {
      int u = i * 256 + tid, row = u >> 3, c8 = u & 7;
      const f32x4* src = reinterpret_cast<const f32x4*>(x + (size_t)(tileM + row) * K + k0 + c8 * 8);
      f32x4 v0 = src[0], v1 = src[1];
      bf16x8 w;
      w[0]=(__bf16)v0[0]; w[1]=(__bf16)v0[1]; w[2]=(__bf16)v0[2]; w[3]=(__bf16)v0[3];
      w[4]=(__bf16)v1[0]; w[5]=(__bf16)v1[1]; w[6]=(__bf16)v1[2]; w[7]=(__bf16)v1[3];
      int slot = c8 ^ (row & 7);
      *reinterpret_cast<bf16x8*>(&lds_a[row * BK + slot * 8]) = w;
    }
#pragma unroll
    for (int i = 0; i < 4; ++i) {
      int u = i * 256 + tid, row = u >> 3, c8 = u & 7;
      int gn = tileN + row;
      const i32x4* src = reinterpret_cast<const i32x4*>(qw + (size_t)gn * K + k0 + c8 * 8);
      i32x4 q0 = src[0], q1 = src[1];
      float s = scales[gn * NG + g];
      bf16x8 w;
      w[0]=(__bf16)((float)q0[0]*s); w[1]=(__bf16)((float)q0[1]*s);
      w[2]=(__bf16)((float)q0[2]*s); w[3]=(__bf16)((float)q0[3]*s);
      w[4]=(__bf16)((float)q1[0]*s); w[5]=(__bf16)((float)q1[1]*s);
      w[6]=(__bf16)((float)q1[2]*s); w[7]=(__bf16)((float)q1[3]*s);
      int slot = c8 ^ (row & 7);
      *reinterpret_cast<bf16x8*>(&lds_b[row * BK + slot * 8]) = w;
    }
    __syncthreads();
#pragma unroll
    for (int kk = 0; kk < BK; kk += 32) {
      bf16x8 af[4], bfr[4];
#pragma unroll
      for (int m = 0; m < 4; ++m) {
        int row = wr * 64 + m * 16 + l15, slot = ((kk >> 3) + l4) ^ (row & 7);
        af[m] = *reinterpret_cast<const bf16x8*>(&lds_a[row * BK + slot * 8]);
      }
#pragma unroll
      for (int n = 0; n < 4; ++n) {
        int row = wc * 64 + n * 16 + l15, slot = ((kk >> 3) + l4) ^ (row & 7);
        bfr[n] = *reinterpret_cast<const bf16x8*>(&lds_b[row * BK + slot * 8]);
      }
#pragma unroll
      for (int m = 0; m < 4; ++m)
#pragma unroll
        for (int n = 0; n < 4; ++n)
          acc[m][n] = __builtin_amdgcn_mfma_f32_16x16x32_bf16(af[m], bfr[n], acc[m][n], 0, 0, 0);
    }
    __syncthreads();
  }
#pragma unroll
  for (int n = 0; n < 4; ++n) {
    int coln = tileN + wc * 64 + n * 16 + l15;
    float bv = bias[coln];
#pragma unroll
    for (int m = 0; m < 4; ++m) {
      int rbase = tileM + wr * 64 + m * 16 + l4 * 4;
#pragma unroll
      for (int r = 0; r < 4; ++r)
        out[(size_t)(rbase + r) * N + coln] = acc[m][n][r] + bv;
    }
  }
}

// prepass: x fp32 -> bf16 into workspace
__global__ __launch_bounds__(256)
void xcvt(const float* __restrict__ x, __bf16* __restrict__ xb, int n8) {
  const int i = blockIdx.x * blockDim.x + threadIdx.x;
  if (i < n8) {
    const f32x4* p = reinterpret_cast<const f32x4*>(x + (size_t)i * 8);
    f32x4 a = p[0], b = p[1];
    bf16x8 w;
    w[0]=(__bf16)a[0]; w[1]=(__bf16)a[1]; w[2]=(__bf16)a[2]; w[3]=(__bf16)a[3];
    w[4]=(__bf16)b[0]; w[5]=(__bf16)b[1]; w[6]=(__bf16)b[2]; w[7]=(__bf16)b[3];
    *reinterpret_cast<bf16x8*>(xb + (size_t)i * 8) = w;
  }
}

extern "C" void kernel_launch(void* const* d_in, const int* in_sizes, int n_in,
                              void* d_out, int out_size, void* d_ws, size_t ws_size,
                              hipStream_t stream) {
  const float* x      = (const float*)d_in[0];
  const int*   qw     = (const int*)d_in[1];
  const float* scales = (const float*)d_in[2];
  const float* bias   = (const float*)d_in[3];
  float*       out    = (float*)d_out;

  const int OUT = in_sizes[3];            // 11008
  const int IN  = in_sizes[1] / OUT;      // 4096
  const int M   = in_sizes[0] / IN;       // 512
  const int NG  = in_sizes[2] / OUT;      // 32
  const int GS  = IN / NG;                // 128

  const size_t need = (size_t)M * IN * sizeof(__bf16);
  const bool ok = (ws_size >= need) && ((M * IN) % 2048 == 0) &&
                  (M % BM == 0) && (OUT % BN == 0) && (IN % (2 * BK) == 0) &&
                  (GS == 2 * BK) && (NG >= 2);

  if (ok) {
    const int n8 = (M * IN) / 8;
    xcvt<<<(n8 + 255) / 256, 256, 0, stream>>>(x, (__bf16*)d_ws, n8);
    const int gx = OUT / BN;              // 172
    const int gy = M / BM;                // 4
    gptq_gemm_pipe<<<gx * gy, NTHR, 0, stream>>>(
        (const __bf16*)d_ws, qw, scales, bias, out, M, OUT, IN, NG, gy);
  } else {
    dim3 grid(OUT / FBN, M / FBM);
    gptq_gemm_fb<<<grid, 256, 0, stream>>>(x, qw, scales, bias, out, M, OUT, IN, NG, GS);
  }
}

// Round 6
// 136.965 us; speedup vs baseline: 1.5222x; 1.2628x over previous
//
#include <hip/hip_runtime.h>
#include <hip/hip_bf16.h>
#include <stdint.h>

using bf16x8 = __attribute__((ext_vector_type(8))) __bf16;
using f32x4  = __attribute__((ext_vector_type(4))) float;
using i32x4  = __attribute__((ext_vector_type(4))) int;

#define BM 128
#define BN 64
#define BK 64
#define NTHR 512   // 8 waves: 2 (M) x 4 (N); wave tile 64x16

__device__ __forceinline__ void gload_lds16(const void* g, void* l) {
  __builtin_amdgcn_global_load_lds((const __attribute__((address_space(1))) void*)g,
                                   (__attribute__((address_space(3))) void*)l,
                                   16, 0, 0);
}

// ---------------- pipelined kernel (A pre-converted to bf16 in ws) ----------
__global__ __launch_bounds__(NTHR, 4)
void gptq_gemm_pipe(const __bf16* __restrict__ xb, const int* __restrict__ qw,
                    const float* __restrict__ scales, const float* __restrict__ bias,
                    float* __restrict__ out, int M, int N, int K, int NG, int GS, int gy) {
  __shared__ __bf16 As[2][BM * BK];   // 2 x 16 KiB
  __shared__ int    Bs[2][BN * BK];   // 2 x 16 KiB (raw int32)

  const int tid  = threadIdx.x;
  const int lane = tid & 63;
  const int wave = tid >> 6;
  const int wr   = wave >> 2;   // 0..1 (M)
  const int wc   = wave & 3;    // 0..3 (N)

  // XCD-chunked mapping: 43 consecutive wgids per XCD (nwg % 8 == 0).
  // by-innermost decode => all gy M-sharers of a qweight panel on ONE XCD.
  int wgid = blockIdx.x;
  if ((gridDim.x & 7) == 0) {
    const int q = gridDim.x >> 3;
    wgid = (blockIdx.x & 7) * q + (blockIdx.x >> 3);
  }
  const int bx = wgid / gy;
  const int by = wgid % gy;
  const int tileM = by * BM;
  const int tileN = bx * BN;

  const int l15 = lane & 15;
  const int l4  = lane >> 4;

  f32x4 accf[4], part[4];
#pragma unroll
  for (int m = 0; m < 4; ++m) { accf[m] = (f32x4)0.0f; part[m] = (f32x4)0.0f; }

  // staging: 16B units; LDS linear, global source pre-swizzled (m173 pattern)
  auto STAGE = [&](int buf, int k0) {
#pragma unroll
    for (int i = 0; i < 2; ++i) {
      const int u = (i * 8 + wave) * 64 + lane;
      { // A: row=u>>3, slot=u&7 holds global c8 = slot^(row&7)
        const int row = u >> 3, slot = u & 7;
        const int c8 = slot ^ (row & 7);
        gload_lds16(xb + (size_t)(tileM + row) * K + k0 + c8 * 8,
                    &As[buf][(i * 8 + wave) * 512]);
      }
      { // B: row=u>>4, slot4=u&15 holds global c4 = slot4^(row&7)
        const int row = u >> 4, slot4 = u & 15;
        const int c4 = slot4 ^ (row & 7);
        gload_lds16(qw + (size_t)(tileN + row) * K + k0 + c4 * 4,
                    &Bs[buf][(i * 8 + wave) * 256]);
      }
    }
  };

  // per K-step compute: frag build (unscaled dequant) + MFMA into part[]
  auto MFMA_PHASE = [&](const __bf16* As_, const int* Bs_) {
#pragma unroll
    for (int kk = 0; kk < 2; ++kk) {
      const int c8 = kk * 4 + l4;
      bf16x8 af[4];
#pragma unroll
      for (int m = 0; m < 4; ++m) {
        const int row = wr * 64 + m * 16 + l15;
        const int slot = c8 ^ (row & 7);
        af[m] = *reinterpret_cast<const bf16x8*>(&As_[row * BK + slot * 8]);
      }
      const int r  = wc * 16 + l15;
      const int rb = r & 7;
      i32x4 q0 = *reinterpret_cast<const i32x4*>(&Bs_[r * BK + ((2 * c8) ^ rb) * 4]);
      i32x4 q1 = *reinterpret_cast<const i32x4*>(&Bs_[r * BK + ((2 * c8 + 1) ^ rb) * 4]);
      bf16x8 bb;   // q in [0,16): exact in bf16; scale applied per group later
      bb[0] = (__bf16)(float)q0[0]; bb[1] = (__bf16)(float)q0[1];
      bb[2] = (__bf16)(float)q0[2]; bb[3] = (__bf16)(float)q0[3];
      bb[4] = (__bf16)(float)q1[0]; bb[5] = (__bf16)(float)q1[1];
      bb[6] = (__bf16)(float)q1[2]; bb[7] = (__bf16)(float)q1[3];
#pragma unroll
      for (int m = 0; m < 4; ++m)
        part[m] = __builtin_amdgcn_mfma_f32_16x16x32_bf16(af[m], bb, part[m], 0, 0, 0);
    }
  };

  // per-lane scale pointer: col = tileN + wc*16 + l15
  const float* sPtr = scales + (size_t)(tileN + wc * 16 + l15) * NG;

  // circular K phase: co-panel blocks share g0 (L2 dedup), panels de-phased
  const int g0 = (bx * 7) % NG;
  auto wrapg = [&](int g) { while (g >= NG) g -= NG; return g; };

  // ---- prologue: VMEM order = [sc,sc,sc, Se0(4), So0(4)] ----
  float s_cur  = sPtr[g0];
  float s_nxt  = sPtr[wrapg(g0 + 1)];
  float s_nxt2 = sPtr[wrapg(g0 + 2)];
  __builtin_amdgcn_sched_barrier(0);
  STAGE(0, g0 * GS);
  __builtin_amdgcn_sched_barrier(0);
  STAGE(1, g0 * GS + BK);
  __builtin_amdgcn_sched_barrier(0);

  auto groupClose = [&](int i) {
#pragma unroll
    for (int m = 0; m < 4; ++m) { accf[m] += s_cur * part[m]; part[m] = (f32x4)0.0f; }
    s_cur = s_nxt; s_nxt = s_nxt2;
    s_nxt2 = sPtr[wrapg(g0 + i + 3)];          // trailing VMEM (1)
  };

  // ---- peeled iter 0: waits vmcnt(4)/(4) per FIFO trace ----
  {
    const int gn = wrapg(g0 + 1);
    asm volatile("s_waitcnt vmcnt(4)" ::: "memory");   // Se0 landed (So0 younger=4)
    __builtin_amdgcn_s_barrier();
    __builtin_amdgcn_sched_barrier(0);
    MFMA_PHASE(As[0], Bs[0]);
    __builtin_amdgcn_sched_barrier(0);
    __builtin_amdgcn_s_barrier();
    STAGE(0, gn * GS);
    __builtin_amdgcn_sched_barrier(0);
    asm volatile("s_waitcnt vmcnt(4)" ::: "memory");   // So0 landed (Se1 younger=4)
    __builtin_amdgcn_s_barrier();
    __builtin_amdgcn_sched_barrier(0);
    MFMA_PHASE(As[1], Bs[1]);
    __builtin_amdgcn_sched_barrier(0);
    __builtin_amdgcn_s_barrier();
    STAGE(1, gn * GS + BK);
    __builtin_amdgcn_sched_barrier(0);
    groupClose(0);
  }

  // ---- steady loop i = 1..NG-1 ----
  for (int i = 1; i < NG; ++i) {
    const int gn = wrapg(g0 + i + 1);                  // stage target (unused last iter)
    // even: queue [Se(i)4, So(i)4, sc1] -> need Se: vmcnt(5)
    asm volatile("s_waitcnt vmcnt(5)" ::: "memory");
    __builtin_amdgcn_s_barrier();
    __builtin_amdgcn_sched_barrier(0);
    MFMA_PHASE(As[0], Bs[0]);
    __builtin_amdgcn_sched_barrier(0);
    __builtin_amdgcn_s_barrier();
    if (i + 1 < NG) STAGE(0, gn * GS);
    __builtin_amdgcn_sched_barrier(0);
    // odd: queue [So(i)4, sc1, Se(i+1)4] -> need So: vmcnt(5); last iter: [So4, sc1] -> vmcnt(1)
    if (i + 1 < NG) { asm volatile("s_waitcnt vmcnt(5)" ::: "memory"); }
    else            { asm volatile("s_waitcnt vmcnt(1)" ::: "memory"); }
    __builtin_amdgcn_s_barrier();
    __builtin_amdgcn_sched_barrier(0);
    MFMA_PHASE(As[1], Bs[1]);
    __builtin_amdgcn_sched_barrier(0);
    __builtin_amdgcn_s_barrier();
    if (i + 1 < NG) STAGE(1, gn * GS + BK);
    __builtin_amdgcn_sched_barrier(0);
    groupClose(i);
  }

  // ---- epilogue: D row = l4*4 + r, col = l15 ----
  const int col = tileN + wc * 16 + l15;
  const float bv = bias[col];
#pragma unroll
  for (int m = 0; m < 4; ++m) {
    const int rbase = tileM + wr * 64 + m * 16 + l4 * 4;
#pragma unroll
    for (int r = 0; r < 4; ++r)
      out[(size_t)(rbase + r) * N + col] = accf[m][r] + bv;
  }
}

// ---------------- fallback (no usable ws): R1-style, known-correct ----------
#define FBM 128
#define FBN 128
__global__ __launch_bounds__(256)
void gptq_gemm_fb(const float* __restrict__ x, const int* __restrict__ qw,
                  const float* __restrict__ scales, const float* __restrict__ bias,
                  float* __restrict__ out, int M, int N, int K, int NG, int GS) {
  __shared__ __bf16 lds_a[FBM * BK];
  __shared__ __bf16 lds_b[FBN * BK];
  const int tid = threadIdx.x, lane = tid & 63, wave = tid >> 6;
  const int wr = wave >> 1, wc = wave & 1;
  const int tileM = blockIdx.y * FBM, tileN = blockIdx.x * FBN;
  const int l15 = lane & 15, l4 = lane >> 4;
  f32x4 acc[4][4];
#pragma unroll
  for (int m = 0; m < 4; ++m)
#pragma unroll
    for (int n = 0; n < 4; ++n) acc[m][n] = (f32x4)0.0f;
  for (int k0 = 0; k0 < K; k0 += BK) {
    const int g = k0 / GS;
#pragma unroll
    for (int i = 0; i < 4; ++i) {
      int u = i * 256 + tid, row = u >> 3, c8 = u & 7;
      const f32x4* src = reinterpret_cast<const f32x4*>(x + (size_t)(tileM + row) * K + k0 + c8 * 8);
      f32x4 v0 = src[0], v1 = src[1];
      bf16x8 w;
      w[0]=(__bf16)v0[0]; w[1]=(__bf16)v0[1]; w[2]=(__bf16)v0[2]; w[3]=(__bf16)v0[3];
      w[4]=(__bf16)v1[0]; w[5]=(__bf16)v1[1]; w[6]=(__bf16)v1[2]; w[7]=(__bf16)v1[3];
      int slot = c8 ^ (row & 7);
      *reinterpret_cast<bf16x8*>(&lds_a[row * BK + slot * 8]) = w;
    }
#pragma unroll
    for (int i = 0; i < 4; ++i) {
      int u = i * 256 + tid, row = u >> 3, c8 = u & 7;
      int gn = tileN + row;
      const i32x4* src = reinterpret_cast<const i32x4*>(qw + (size_t)gn * K + k0 + c8 * 8);
      i32x4 q0 = src[0], q1 = src[1];
      float s = scales[gn * NG + g];
      bf16x8 w;
      w[0]=(__bf16)((float)q0[0]*s); w[1]=(__bf16)((float)q0[1]*s);
      w[2]=(__bf16)((float)q0[2]*s); w[3]=(__bf16)((float)q0[3]*s);
      w[4]=(__bf16)((float)q1[0]*s); w[5]=(__bf16)((float)q1[1]*s);
      w[6]=(__bf16)((float)q1[2]*s); w[7]=(__bf16)((float)q1[3]*s);
      int slot = c8 ^ (row & 7);
      *reinterpret_cast<bf16x8*>(&lds_b[row * BK + slot * 8]) = w;
    }
    __syncthreads();
#pragma unroll
    for (int kk = 0; kk < BK; kk += 32) {
      bf16x8 af[4], bfr[4];
#pragma unroll
      for (int m = 0; m < 4; ++m) {
        int row = wr * 64 + m * 16 + l15, slot = ((kk >> 3) + l4) ^ (row & 7);
        af[m] = *reinterpret_cast<const bf16x8*>(&lds_a[row * BK + slot * 8]);
      }
#pragma unroll
      for (int n = 0; n < 4; ++n) {
        int row = wc * 64 + n * 16 + l15, slot = ((kk >> 3) + l4) ^ (row & 7);
        bfr[n] = *reinterpret_cast<const bf16x8*>(&lds_b[row * BK + slot * 8]);
      }
#pragma unroll
      for (int m = 0; m < 4; ++m)
#pragma unroll
        for (int n = 0; n < 4; ++n)
          acc[m][n] = __builtin_amdgcn_mfma_f32_16x16x32_bf16(af[m], bfr[n], acc[m][n], 0, 0, 0);
    }
    __syncthreads();
  }
#pragma unroll
  for (int n = 0; n < 4; ++n) {
    int coln = tileN + wc * 64 + n * 16 + l15;
    float bv = bias[coln];
#pragma unroll
    for (int m = 0; m < 4; ++m) {
      int rbase = tileM + wr * 64 + m * 16 + l4 * 4;
#pragma unroll
      for (int r = 0; r < 4; ++r)
        out[(size_t)(rbase + r) * N + coln] = acc[m][n][r] + bv;
    }
  }
}

// prepass: x fp32 -> bf16 into workspace
__global__ __launch_bounds__(256)
void xcvt(const float* __restrict__ x, __bf16* __restrict__ xb, int n8) {
  const int i = blockIdx.x * blockDim.x + threadIdx.x;
  if (i < n8) {
    const f32x4* p = reinterpret_cast<const f32x4*>(x + (size_t)i * 8);
    f32x4 a = p[0], b = p[1];
    bf16x8 w;
    w[0]=(__bf16)a[0]; w[1]=(__bf16)a[1]; w[2]=(__bf16)a[2]; w[3]=(__bf16)a[3];
    w[4]=(__bf16)b[0]; w[5]=(__bf16)b[1]; w[6]=(__bf16)b[2]; w[7]=(__bf16)b[3];
    *reinterpret_cast<bf16x8*>(xb + (size_t)i * 8) = w;
  }
}

extern "C" void kernel_launch(void* const* d_in, const int* in_sizes, int n_in,
                              void* d_out, int out_size, void* d_ws, size_t ws_size,
                              hipStream_t stream) {
  const float* x      = (const float*)d_in[0];
  const int*   qw     = (const int*)d_in[1];
  const float* scales = (const float*)d_in[2];
  const float* bias   = (const float*)d_in[3];
  float*       out    = (float*)d_out;

  const int OUT = in_sizes[3];            // 11008
  const int IN  = in_sizes[1] / OUT;      // 4096
  const int M   = in_sizes[0] / IN;       // 512
  const int NG  = in_sizes[2] / OUT;      // 32
  const int GS  = IN / NG;                // 128

  const size_t need = (size_t)M * IN * sizeof(__bf16);
  const bool ok = (ws_size >= need) && ((M * IN) % 2048 == 0) &&
                  (M % BM == 0) && (OUT % BN == 0) && (IN % (2 * BK) == 0) &&
                  (GS == 2 * BK) && (NG >= 2);

  if (ok) {
    const int n8 = (M * IN) / 8;
    xcvt<<<(n8 + 255) / 256, 256, 0, stream>>>(x, (__bf16*)d_ws, n8);
    const int gx = OUT / BN;              // 172
    const int gy = M / BM;                // 4
    gptq_gemm_pipe<<<gx * gy, NTHR, 0, stream>>>(
        (const __bf16*)d_ws, qw, scales, bias, out, M, OUT, IN, NG, GS, gy);
  } else {
    dim3 grid(OUT / FBN, M / FBM);
    gptq_gemm_fb<<<grid, 256, 0, stream>>>(x, qw, scales, bias, out, M, OUT, IN, NG, GS);
  }
}

// Round 7
// 121.001 us; speedup vs baseline: 1.7230x; 1.1319x over previous
//
#include <hip/hip_runtime.h>
#include <hip/hip_bf16.h>
#include <stdint.h>

using bf16x8 = __attribute__((ext_vector_type(8))) __bf16;
using f32x4  = __attribute__((ext_vector_type(4))) float;
using i32x4  = __attribute__((ext_vector_type(4))) int;

__device__ __forceinline__ void gload_lds16(const void* g, void* l) {
  __builtin_amdgcn_global_load_lds((const __attribute__((address_space(1))) void*)g,
                                   (__attribute__((address_space(3))) void*)l,
                                   16, 0, 0);
}

// ======================= packed-operand GEMM path =======================
#define GBM 128
#define GBN 128
#define GBK 64
#define GTHR 256   // 4 waves, 2x2; wave tile 64x64, acc 4x4

// Pack B: qweight int32 + scales -> bf16, tile-contiguous [panel][t][unit],
// unit(row,slot) holds W[row][ (slot^(row&7))*8 .. +8 ] (pre-swizzled for LDS).
__global__ __launch_bounds__(256)
void pack_b(const int* __restrict__ qw, const float* __restrict__ scales,
            __bf16* __restrict__ wsB, int K, int NG, int GS, int nT) {
  const int p = blockIdx.x / nT;
  const int t = blockIdx.x % nT;
  const int g = (t * GBK) / GS;
  __bf16* dst = wsB + ((size_t)p * nT + t) * (GBN * GBK);
#pragma unroll
  for (int i = 0; i < 4; ++i) {
    const int u = i * 256 + threadIdx.x;    // 0..1023
    const int row = u >> 3, slot = u & 7;
    const int c8 = slot ^ (row & 7);
    const int n = p * GBN + row;
    const i32x4* src = reinterpret_cast<const i32x4*>(qw + (size_t)n * K + t * GBK + c8 * 8);
    i32x4 q0 = src[0], q1 = src[1];
    const float s = scales[(size_t)n * NG + g];
    bf16x8 w;
    w[0] = (__bf16)((float)q0[0] * s); w[1] = (__bf16)((float)q0[1] * s);
    w[2] = (__bf16)((float)q0[2] * s); w[3] = (__bf16)((float)q0[3] * s);
    w[4] = (__bf16)((float)q1[0] * s); w[5] = (__bf16)((float)q1[1] * s);
    w[6] = (__bf16)((float)q1[2] * s); w[7] = (__bf16)((float)q1[3] * s);
    *reinterpret_cast<bf16x8*>(dst + (size_t)u * 8) = w;
  }
}

// Pack A: x fp32 -> bf16, tile-contiguous [by][t][unit], same swizzle.
__global__ __launch_bounds__(256)
void xcvt_p(const float* __restrict__ x, __bf16* __restrict__ wsA, int K, int nT) {
  const int u = blockIdx.x * 256 + threadIdx.x;        // global unit
  const int uu = u & 1023;
  const int t  = (u >> 10) % nT;
  const int by = (u >> 10) / nT;
  const int row = uu >> 3, slot = uu & 7;
  const int c8 = slot ^ (row & 7);
  const f32x4* src = reinterpret_cast<const f32x4*>(
      x + (size_t)(by * GBM + row) * K + t * GBK + c8 * 8);
  f32x4 a = src[0], b = src[1];
  bf16x8 w;
  w[0] = (__bf16)a[0]; w[1] = (__bf16)a[1]; w[2] = (__bf16)a[2]; w[3] = (__bf16)a[3];
  w[4] = (__bf16)b[0]; w[5] = (__bf16)b[1]; w[6] = (__bf16)b[2]; w[7] = (__bf16)b[3];
  *reinterpret_cast<bf16x8*>(wsA + (size_t)u * 8) = w;
}

__global__ __launch_bounds__(GTHR, 4)
void gemm_packed(const __bf16* __restrict__ wsA, const __bf16* __restrict__ wsB,
                 const float* __restrict__ bias, float* __restrict__ out,
                 int N, int K, int gy) {
  __shared__ __bf16 As[2][GBM * GBK];   // 2 x 16 KiB
  __shared__ __bf16 Bs[2][GBN * GBK];   // 2 x 16 KiB

  const int tid  = threadIdx.x;
  const int lane = tid & 63;
  const int wv   = tid >> 6;
  const int wr   = wv >> 1;   // 0..1
  const int wc   = wv & 1;    // 0..1

  // XCD-chunked mapping (grid 344 = 8*43), by-innermost
  int wgid = blockIdx.x;
  if ((gridDim.x & 7) == 0) {
    const int q = gridDim.x >> 3;
    wgid = (blockIdx.x & 7) * q + (blockIdx.x >> 3);
  }
  const int bx = wgid / gy;
  const int by = wgid % gy;

  const int l15 = lane & 15;
  const int l4  = lane >> 4;
  const int nT  = K / GBK;

  const __bf16* srcA = wsA + (size_t)by * nT * (GBM * GBK);
  const __bf16* srcB = wsB + (size_t)bx * nT * (GBN * GBK);

  f32x4 acc[4][4];
#pragma unroll
  for (int m = 0; m < 4; ++m)
#pragma unroll
    for (int n = 0; n < 4; ++n) acc[m][n] = (f32x4)0.0f;

  // identity staging: contiguous global stream -> linear LDS (swizzle pre-baked)
  auto STAGE = [&](int buf, int t) {
    const __bf16* a = srcA + (size_t)t * (GBM * GBK);
    const __bf16* b = srcB + (size_t)t * (GBN * GBK);
#pragma unroll
    for (int i = 0; i < 4; ++i) {
      const int ub = (i * 4 + wv) * 64;       // wave-uniform base unit
      gload_lds16(a + (size_t)(ub + lane) * 8, &As[buf][ub * 8]);
      gload_lds16(b + (size_t)(ub + lane) * 8, &Bs[buf][ub * 8]);
    }
  };

  auto MF = [&](const __bf16* A_, const __bf16* B_) {
#pragma unroll
    for (int kk = 0; kk < 2; ++kk) {
      const int c8 = kk * 4 + l4;
      bf16x8 af[4], bf_[4];
#pragma unroll
      for (int m = 0; m < 4; ++m) {
        const int row = wr * 64 + m * 16 + l15;
        const int slot = c8 ^ (row & 7);
        af[m] = *reinterpret_cast<const bf16x8*>(&A_[row * GBK + slot * 8]);
      }
#pragma unroll
      for (int n = 0; n < 4; ++n) {
        const int col = wc * 64 + n * 16 + l15;
        const int slot = c8 ^ (col & 7);
        bf_[n] = *reinterpret_cast<const bf16x8*>(&B_[col * GBK + slot * 8]);
      }
#pragma unroll
      for (int m = 0; m < 4; ++m)
#pragma unroll
        for (int n = 0; n < 4; ++n)
          acc[m][n] = __builtin_amdgcn_mfma_f32_16x16x32_bf16(af[m], bf_[n], acc[m][n], 0, 0, 0);
    }
  };

  STAGE(0, 0);
  STAGE(1, 1);                      // 16 outstanding per wave

  int cur = 0;
  for (int t = 0; t < nT; ++t) {
    if (t + 1 < nT) { asm volatile("s_waitcnt vmcnt(8)" ::: "memory"); }
    else            { asm volatile("s_waitcnt vmcnt(0)" ::: "memory"); }
    __builtin_amdgcn_s_barrier();
    __builtin_amdgcn_sched_barrier(0);
    MF(As[cur], Bs[cur]);
    __builtin_amdgcn_sched_barrier(0);
    __builtin_amdgcn_s_barrier();   // buf cur free
    if (t + 2 < nT) STAGE(cur, t + 2);
    __builtin_amdgcn_sched_barrier(0);
    cur ^= 1;
  }

  // epilogue: D row = l4*4 + r, col = l15 (verified layout)
  const int tileM = by * GBM, tileN = bx * GBN;
#pragma unroll
  for (int n = 0; n < 4; ++n) {
    const int col = tileN + wc * 64 + n * 16 + l15;
    const float bv = bias[col];
#pragma unroll
    for (int m = 0; m < 4; ++m) {
      const int rbase = tileM + wr * 64 + m * 16 + l4 * 4;
#pragma unroll
      for (int r = 0; r < 4; ++r)
        out[(size_t)(rbase + r) * N + col] = acc[m][n][r] + bv;
    }
  }
}

// ======================= R6 pipe path (fallback, proven) =======================
#define BM 128
#define BN 64
#define BK 64
#define NTHR 512

__global__ __launch_bounds__(NTHR, 4)
void gptq_gemm_pipe(const __bf16* __restrict__ xb, const int* __restrict__ qw,
                    const float* __restrict__ scales, const float* __restrict__ bias,
                    float* __restrict__ out, int M, int N, int K, int NG, int GS, int gy) {
  __shared__ __bf16 As[2][BM * BK];
  __shared__ int    Bs[2][BN * BK];

  const int tid  = threadIdx.x;
  const int lane = tid & 63;
  const int wave = tid >> 6;
  const int wr   = wave >> 2;
  const int wc   = wave & 3;

  int wgid = blockIdx.x;
  if ((gridDim.x & 7) == 0) {
    const int q = gridDim.x >> 3;
    wgid = (blockIdx.x & 7) * q + (blockIdx.x >> 3);
  }
  const int bx = wgid / gy;
  const int by = wgid % gy;
  const int tileM = by * BM;
  const int tileN = bx * BN;

  const int l15 = lane & 15;
  const int l4  = lane >> 4;

  f32x4 accf[4], part[4];
#pragma unroll
  for (int m = 0; m < 4; ++m) { accf[m] = (f32x4)0.0f; part[m] = (f32x4)0.0f; }

  auto STAGE = [&](int buf, int k0) {
#pragma unroll
    for (int i = 0; i < 2; ++i) {
      const int u = (i * 8 + wave) * 64 + lane;
      {
        const int row = u >> 3, slot = u & 7;
        const int c8 = slot ^ (row & 7);
        gload_lds16(xb + (size_t)(tileM + row) * K + k0 + c8 * 8,
                    &As[buf][(i * 8 + wave) * 512]);
      }
      {
        const int row = u >> 4, slot4 = u & 15;
        const int c4 = slot4 ^ (row & 7);
        gload_lds16(qw + (size_t)(tileN + row) * K + k0 + c4 * 4,
                    &Bs[buf][(i * 8 + wave) * 256]);
      }
    }
  };

  auto MFMA_PHASE = [&](const __bf16* As_, const int* Bs_) {
#pragma unroll
    for (int kk = 0; kk < 2; ++kk) {
      const int c8 = kk * 4 + l4;
      bf16x8 af[4];
#pragma unroll
      for (int m = 0; m < 4; ++m) {
        const int row = wr * 64 + m * 16 + l15;
        const int slot = c8 ^ (row & 7);
        af[m] = *reinterpret_cast<const bf16x8*>(&As_[row * BK + slot * 8]);
      }
      const int r  = wc * 16 + l15;
      const int rb = r & 7;
      i32x4 q0 = *reinterpret_cast<const i32x4*>(&Bs_[r * BK + ((2 * c8) ^ rb) * 4]);
      i32x4 q1 = *reinterpret_cast<const i32x4*>(&Bs_[r * BK + ((2 * c8 + 1) ^ rb) * 4]);
      bf16x8 bb;
      bb[0] = (__bf16)(float)q0[0]; bb[1] = (__bf16)(float)q0[1];
      bb[2] = (__bf16)(float)q0[2]; bb[3] = (__bf16)(float)q0[3];
      bb[4] = (__bf16)(float)q1[0]; bb[5] = (__bf16)(float)q1[1];
      bb[6] = (__bf16)(float)q1[2]; bb[7] = (__bf16)(float)q1[3];
#pragma unroll
      for (int m = 0; m < 4; ++m)
        part[m] = __builtin_amdgcn_mfma_f32_16x16x32_bf16(af[m], bb, part[m], 0, 0, 0);
    }
  };

  const float* sPtr = scales + (size_t)(tileN + wc * 16 + l15) * NG;
  const int g0 = (bx * 7) % NG;
  auto wrapg = [&](int g) { while (g >= NG) g -= NG; return g; };

  float s_cur  = sPtr[g0];
  float s_nxt  = sPtr[wrapg(g0 + 1)];
  float s_nxt2 = sPtr[wrapg(g0 + 2)];
  __builtin_amdgcn_sched_barrier(0);
  STAGE(0, g0 * GS);
  __builtin_amdgcn_sched_barrier(0);
  STAGE(1, g0 * GS + BK);
  __builtin_amdgcn_sched_barrier(0);

  auto groupClose = [&](int i) {
#pragma unroll
    for (int m = 0; m < 4; ++m) { accf[m] += s_cur * part[m]; part[m] = (f32x4)0.0f; }
    s_cur = s_nxt; s_nxt = s_nxt2;
    s_nxt2 = sPtr[wrapg(g0 + i + 3)];
  };

  {
    const int gn = wrapg(g0 + 1);
    asm volatile("s_waitcnt vmcnt(4)" ::: "memory");
    __builtin_amdgcn_s_barrier();
    __builtin_amdgcn_sched_barrier(0);
    MFMA_PHASE(As[0], Bs[0]);
    __builtin_amdgcn_sched_barrier(0);
    __builtin_amdgcn_s_barrier();
    STAGE(0, gn * GS);
    __builtin_amdgcn_sched_barrier(0);
    asm volatile("s_waitcnt vmcnt(4)" ::: "memory");
    __builtin_amdgcn_s_barrier();
    __builtin_amdgcn_sched_barrier(0);
    MFMA_PHASE(As[1], Bs[1]);
    __builtin_amdgcn_sched_barrier(0);
    __builtin_amdgcn_s_barrier();
    STAGE(1, gn * GS + BK);
    __builtin_amdgcn_sched_barrier(0);
    groupClose(0);
  }

  for (int i = 1; i < NG; ++i) {
    const int gn = wrapg(g0 + i + 1);
    asm volatile("s_waitcnt vmcnt(5)" ::: "memory");
    __builtin_amdgcn_s_barrier();
    __builtin_amdgcn_sched_barrier(0);
    MFMA_PHASE(As[0], Bs[0]);
    __builtin_amdgcn_sched_barrier(0);
    __builtin_amdgcn_s_barrier();
    if (i + 1 < NG) STAGE(0, gn * GS);
    __builtin_amdgcn_sched_barrier(0);
    if (i + 1 < NG) { asm volatile("s_waitcnt vmcnt(5)" ::: "memory"); }
    else            { asm volatile("s_waitcnt vmcnt(1)" ::: "memory"); }
    __builtin_amdgcn_s_barrier();
    __builtin_amdgcn_sched_barrier(0);
    MFMA_PHASE(As[1], Bs[1]);
    __builtin_amdgcn_sched_barrier(0);
    __builtin_amdgcn_s_barrier();
    if (i + 1 < NG) STAGE(1, gn * GS + BK);
    __builtin_amdgcn_sched_barrier(0);
    groupClose(i);
  }

  const int col = tileN + wc * 16 + l15;
  const float bv = bias[col];
#pragma unroll
  for (int m = 0; m < 4; ++m) {
    const int rbase = tileM + wr * 64 + m * 16 + l4 * 4;
#pragma unroll
    for (int r = 0; r < 4; ++r)
      out[(size_t)(rbase + r) * N + col] = accf[m][r] + bv;
  }
}

__global__ __launch_bounds__(256)
void xcvt(const float* __restrict__ x, __bf16* __restrict__ xb, int n8) {
  const int i = blockIdx.x * blockDim.x + threadIdx.x;
  if (i < n8) {
    const f32x4* p = reinterpret_cast<const f32x4*>(x + (size_t)i * 8);
    f32x4 a = p[0], b = p[1];
    bf16x8 w;
    w[0]=(__bf16)a[0]; w[1]=(__bf16)a[1]; w[2]=(__bf16)a[2]; w[3]=(__bf16)a[3];
    w[4]=(__bf16)b[0]; w[5]=(__bf16)b[1]; w[6]=(__bf16)b[2]; w[7]=(__bf16)b[3];
    *reinterpret_cast<bf16x8*>(xb + (size_t)i * 8) = w;
  }
}

// ======================= last-resort fallback =======================
#define FBM 128
#define FBN 128
__global__ __launch_bounds__(256)
void gptq_gemm_fb(const float* __restrict__ x, const int* __restrict__ qw,
                  const float* __restrict__ scales, const float* __restrict__ bias,
                  float* __restrict__ out, int M, int N, int K, int NG, int GS) {
  __shared__ __bf16 lds_a[FBM * BK];
  __shared__ __bf16 lds_b[FBN * BK];
  const int tid = threadIdx.x, lane = tid & 63, wave = tid >> 6;
  const int wr = wave >> 1, wc = wave & 1;
  const int tileM = blockIdx.y * FBM, tileN = blockIdx.x * FBN;
  const int l15 = lane & 15, l4 = lane >> 4;
  f32x4 acc[4][4];
#pragma unroll
  for (int m = 0; m < 4; ++m)
#pragma unroll
    for (int n = 0; n < 4; ++n) acc[m][n] = (f32x4)0.0f;
  for (int k0 = 0; k0 < K; k0 += BK) {
    const int g = k0 / GS;
#pragma unroll
    for (int i = 0; i < 4; ++i) {
      int u = i * 256 + tid, row = u >> 3, c8 = u & 7;
      const f32x4* src = reinterpret_cast<const f32x4*>(x + (size_t)(tileM + row) * K + k0 + c8 * 8);
      f32x4 v0 = src[0], v1 = src[1];
      bf16x8 w;
      w[0]=(__bf16)v0[0]; w[1]=(__bf16)v0[1]; w[2]=(__bf16)v0[2]; w[3]=(__bf16)v0[3];
      w[4]=(__bf16)v1[0]; w[5]=(__bf16)v1[1]; w[6]=(__bf16)v1[2]; w[7]=(__bf16)v1[3];
      int slot = c8 ^ (row & 7);
      *reinterpret_cast<bf16x8*>(&lds_a[row * BK + slot * 8]) = w;
    }
#pragma unroll
    for (int i = 0; i < 4; ++i) {
      int u = i * 256 + tid, row = u >> 3, c8 = u & 7;
      int gn = tileN + row;
      const i32x4* src = reinterpret_cast<const i32x4*>(qw + (size_t)gn * K + k0 + c8 * 8);
      i32x4 q0 = src[0], q1 = src[1];
      float s = scales[gn * NG + g];
      bf16x8 w;
      w[0]=(__bf16)((float)q0[0]*s); w[1]=(__bf16)((float)q0[1]*s);
      w[2]=(__bf16)((float)q0[2]*s); w[3]=(__bf16)((float)q0[3]*s);
      w[4]=(__bf16)((float)q1[0]*s); w[5]=(__bf16)((float)q1[1]*s);
      w[6]=(__bf16)((float)q1[2]*s); w[7]=(__bf16)((float)q1[3]*s);
      int slot = c8 ^ (row & 7);
      *reinterpret_cast<bf16x8*>(&lds_b[row * BK + slot * 8]) = w;
    }
    __syncthreads();
#pragma unroll
    for (int kk = 0; kk < BK; kk += 32) {
      bf16x8 af[4], bfr[4];
#pragma unroll
      for (int m = 0; m < 4; ++m) {
        int row = wr * 64 + m * 16 + l15, slot = ((kk >> 3) + l4) ^ (row & 7);
        af[m] = *reinterpret_cast<const bf16x8*>(&lds_a[row * BK + slot * 8]);
      }
#pragma unroll
      for (int n = 0; n < 4; ++n) {
        int row = wc * 64 + n * 16 + l15, slot = ((kk >> 3) + l4) ^ (row & 7);
        bfr[n] = *reinterpret_cast<const bf16x8*>(&lds_b[row * BK + slot * 8]);
      }
#pragma unroll
      for (int m = 0; m < 4; ++m)
#pragma unroll
        for (int n = 0; n < 4; ++n)
          acc[m][n] = __builtin_amdgcn_mfma_f32_16x16x32_bf16(af[m], bfr[n], acc[m][n], 0, 0, 0);
    }
    __syncthreads();
  }
#pragma unroll
  for (int n = 0; n < 4; ++n) {
    int coln = tileN + wc * 64 + n * 16 + l15;
    float bv = bias[coln];
#pragma unroll
    for (int m = 0; m < 4; ++m) {
      int rbase = tileM + wr * 64 + m * 16 + l4 * 4;
#pragma unroll
      for (int r = 0; r < 4; ++r)
        out[(size_t)(rbase + r) * N + coln] = acc[m][n][r] + bv;
    }
  }
}

extern "C" void kernel_launch(void* const* d_in, const int* in_sizes, int n_in,
                              void* d_out, int out_size, void* d_ws, size_t ws_size,
                              hipStream_t stream) {
  const float* x      = (const float*)d_in[0];
  const int*   qw     = (const int*)d_in[1];
  const float* scales = (const float*)d_in[2];
  const float* bias   = (const float*)d_in[3];
  float*       out    = (float*)d_out;

  const int OUT = in_sizes[3];            // 11008
  const int IN  = in_sizes[1] / OUT;      // 4096
  const int M   = in_sizes[0] / IN;       // 512
  const int NG  = in_sizes[2] / OUT;      // 32
  const int GS  = IN / NG;                // 128

  const size_t needB = (size_t)OUT * IN * sizeof(__bf16);   // 90.2 MB
  const size_t needA = (size_t)M * IN * sizeof(__bf16);     // 4.2 MB
  const int nT = IN / GBK;

  const bool ok_packed =
      (ws_size >= needB + needA) && (M % GBM == 0) && (OUT % GBN == 0) &&
      (IN % (2 * GBK) == 0) && (GS == 128) && ((M / GBM) > 0);
  const bool ok_pipe =
      (ws_size >= needA) && ((M * IN) % 2048 == 0) && (M % BM == 0) &&
      (OUT % BN == 0) && (IN % (2 * BK) == 0) && (GS == 2 * BK) && (NG >= 2);

  if (ok_packed) {
    __bf16* wsB = (__bf16*)d_ws;
    __bf16* wsA = (__bf16*)((char*)d_ws + needB);
    const int P = OUT / GBN;              // 86
    pack_b<<<P * nT, 256, 0, stream>>>(qw, scales, wsB, IN, NG, GS, nT);
    const int unitsA = (M / GBM) * nT * 1024;
    xcvt_p<<<unitsA / 256, 256, 0, stream>>>(x, wsA, IN, nT);
    const int gy = M / GBM;               // 4
    gemm_packed<<<P * gy, GTHR, 0, stream>>>(wsA, wsB, bias, out, OUT, IN, gy);
  } else if (ok_pipe) {
    const int n8 = (M * IN) / 8;
    xcvt<<<(n8 + 255) / 256, 256, 0, stream>>>(x, (__bf16*)d_ws, n8);
    const int gx = OUT / BN;
    const int gy = M / BM;
    gptq_gemm_pipe<<<gx * gy, NTHR, 0, stream>>>(
        (const __bf16*)d_ws, qw, scales, bias, out, M, OUT, IN, NG, GS, gy);
  } else {
    dim3 grid(OUT / FBN, M / FBM);
    gptq_gemm_fb<<<grid, 256, 0, stream>>>(x, qw, scales, bias, out, M, OUT, IN, NG, GS);
  }
}